// Round 17
// baseline (94.683 us; speedup 1.0000x reference)
//
#include <hip/hip_runtime.h>
#include <hip/hip_bf16.h>

#define DIM 1024
#define STATE 256
#define BATCH 4
#define SEQ 4096
#define M_TOT (BATCH * SEQ)  // 16384

typedef short short8 __attribute__((ext_vector_type(8)));
typedef float f32x4 __attribute__((ext_vector_type(4)));

__device__ __forceinline__ unsigned short f2bf(float f) {
  unsigned int u = __float_as_uint(f);
  u += 0x7fff + ((u >> 16) & 1);  // RNE
  return (unsigned short)(u >> 16);
}

__device__ __forceinline__ float bf2f(unsigned short u) {
  return __uint_as_float((unsigned int)u << 16);
}

__device__ __forceinline__ void gl_lds16(const void* g, void* l) {
  __builtin_amdgcn_global_load_lds(
      (const __attribute__((address_space(1))) void*)g,
      (__attribute__((address_space(3))) void*)l, 16, 0, 0);
}

#define C2F 2.8853900817779268f   // 2*log2(e)
#define LOG2EF 1.4426950408889634f
#define VMC(N) asm volatile("s_waitcnt vmcnt(" #N ")" ::: "memory")

// ---------------- convert_w: Bw -> bwb ; [Cw|Dw] -> wob (r16, unchanged) -----
__global__ __launch_bounds__(256) void convert_w(
    const float* __restrict__ Bw, const float* __restrict__ Cw,
    const float* __restrict__ Dw, unsigned short* __restrict__ bwb,
    unsigned short* __restrict__ wob) {
  const int bx = blockIdx.x;
  const int t = threadIdx.x;
  if (bx < 256) {
    const int c = t * 4;
    const float4 v = *(const float4*)(Bw + (size_t)bx * DIM + c);
    *(ushort4*)(bwb + (size_t)bx * DIM + c) =
        make_ushort4(f2bf(v.x), f2bf(v.y), f2bf(v.z), f2bf(v.w));
  } else {
    const int e0 = (bx - 256) * 4;
#pragma unroll
    for (int rr = 0; rr < 4; ++rr) {
      const int e = e0 + rr;
      if (t < 64) {
        const float4 v = *(const float4*)(Cw + (size_t)e * STATE + t * 4);
        *(ushort4*)(wob + (size_t)e * 1280 + t * 4) =
            make_ushort4(f2bf(v.x), f2bf(v.y), f2bf(v.z), f2bf(v.w));
      }
      const float4 v = *(const float4*)(Dw + (size_t)e * DIM + t * 4);
      *(ushort4*)(wob + (size_t)e * 1280 + 256 + t * 4) =
          make_ushort4(f2bf(v.x), f2bf(v.y), f2bf(v.z), f2bf(v.w));
    }
  }
}

// ---------------- gemm_GX v4.1 (r15/r16, unchanged): G + xb ------------------
__global__ __launch_bounds__(256, 2) void gemm_GX(
    const float* __restrict__ x,             // [16384][1024] f32
    const unsigned short* __restrict__ bwb,  // [256][1024] bf16
    const float* __restrict__ Bb,            // [256]
    const float* __restrict__ A,             // [256]
    unsigned short* __restrict__ G,          // [16384][256] bf16 (out)
    unsigned short* __restrict__ xb)         // [16384][1024] bf16 (out)
{
  __shared__ char lds[81920];  // 2 slots x 40960 (A 8KB @0, B 32KB @8192)

  const int tid = threadIdx.x;
  const int wave = tid >> 6;
  const int lane = tid & 63;
  const int lr = lane & 15;
  const int lk = lane >> 4;
  const int m0 = blockIdx.x * 32;

  f32x4 acc[2][4];
#pragma unroll
  for (int i = 0; i < 2; ++i)
#pragma unroll
    for (int j = 0; j < 4; ++j) acc[i][j] = (f32x4){0.f, 0.f, 0.f, 0.f};

  const char* xB  = (const char*)x;
  const char* bwB = (const char*)bwb;
  char* xbB = (char*)xb;

  auto stage = [&](int kt) {
    if (kt >= 16) return;
    char* slot = lds + (kt & 1) * 40960;
#pragma unroll
    for (int i = 0; i < 2; ++i) {   // A: [32 rows][256B f32], XOR(r&7)
      const int s = i * 256 + tid;
      const int r = s >> 4;
      const int c = (s & 15) ^ (r & 7);
      gl_lds16(xB + (size_t)(m0 + r) * 4096 + (size_t)kt * 256 + c * 16,
               slot + i * 4096 + wave * 1024);
    }
#pragma unroll
    for (int i = 0; i < 8; ++i) {   // B: [256 rows][128B bf16], XOR(r&7)
      const int s = i * 256 + tid;
      const int r = s >> 3;
      const int c = (s & 7) ^ (r & 7);
      gl_lds16(bwB + (size_t)r * 2048 + (size_t)kt * 128 + c * 16,
               slot + 8192 + i * 4096 + wave * 1024);
    }
  };

  stage(0);
  VMC(0);
  __builtin_amdgcn_s_barrier();
  stage(1);

  for (int t = 0; t < 16; ++t) {
    const char* As = lds + (t & 1) * 40960;
    const char* Bs = As + 8192;

    short8 af[2][2];  // [kk][f]
#pragma unroll
    for (int kk = 0; kk < 2; ++kk)
#pragma unroll
      for (int f = 0; f < 2; ++f) {
        const int row = f * 16 + lr;
        const int sw = row & 7;
        const f32x4 a0 = *(const f32x4*)(As + row * 256 + (((kk * 8 + 2 * lk)     ^ sw) << 4));
        const f32x4 a1 = *(const f32x4*)(As + row * 256 + (((kk * 8 + 2 * lk + 1) ^ sw) << 4));
        short8 v;
#pragma unroll
        for (int j = 0; j < 4; ++j) {
          v[j]     = (short)f2bf(a0[j]);
          v[4 + j] = (short)f2bf(a1[j]);
        }
        af[kk][f] = v;
      }

    if ((t & 3) == wave) {  // early xb store
#pragma unroll
      for (int kk = 0; kk < 2; ++kk)
#pragma unroll
        for (int f = 0; f < 2; ++f) {
          const int row = f * 16 + lr;
          *(short8*)(xbB + (size_t)(m0 + row) * 2048 +
                     (size_t)t * 128 + kk * 64 + lk * 16) = af[kk][f];
        }
    }

    short8 bfr[2][4];
#pragma unroll
    for (int kk = 0; kk < 2; ++kk)
#pragma unroll
      for (int fj = 0; fj < 4; ++fj) {
        const int n = wave * 64 + fj * 16 + lr;
        bfr[kk][fj] = *(const short8*)(Bs + n * 128 + (((kk * 4 + lk) ^ (n & 7)) << 4));
      }
#pragma unroll
    for (int kk = 0; kk < 2; ++kk)
#pragma unroll
      for (int f = 0; f < 2; ++f)
#pragma unroll
        for (int fj = 0; fj < 4; ++fj)
          acc[f][fj] = __builtin_amdgcn_mfma_f32_16x16x32_bf16(
              af[kk][f], bfr[kk][fj], acc[f][fj], 0, 0, 0);

    if (t < 15) {
      VMC(0);
      __builtin_amdgcn_s_barrier();
      stage(t + 2);
    }
  }

#pragma unroll
  for (int fj = 0; fj < 4; ++fj) {
    const int cg = wave * 64 + fj * 16 + lr;
    const float bbv = fmaf(Bb[cg], C2F,
                           C2F * __builtin_amdgcn_exp2f(A[cg] * LOG2EF));
#pragma unroll
    for (int f = 0; f < 2; ++f)
#pragma unroll
      for (int j = 0; j < 4; ++j) {
        const int rg = m0 + f * 16 + lk * 4 + j;
        G[(size_t)rg * STATE + cg] = f2bf(fmaf(acc[f][fj][j], C2F, bbv));
      }
  }
}

// ---------------- gemm_out v5: ILP scan head + reordered frozen K-loop -------
// Phase 1 (scan): 512 thr = 2 slots x 256 channels; thread (s,n) runs TWO
// interleaved 128-step chains (chunks s and s+2 of the block's 256 rows,
// 64 warmup + 64 emit each) -> dependent-chain latency pipelined (~2x faster
// than r16's single 192-step chain). Batch-start chunk (T0==0, s==0) has
// nw=0/64 steps (wave-uniform). Phase 2: EXACT r6 K-loop, tiles REORDERED
// t_ord 0..15 -> kt 4..19 (xb), 16..19 -> kt 0..3 (stb) so the prologue
// staging (xb/wob only) issues BEFORE the scan and fills under it; the
// stb-dependent tiles stage last, long after the scan's VMC(0)+barrier.
#define PH(TILE, Q, STG, VMST)                                                 \
  do {                                                                         \
    const char* As = lds + ((TILE) & 1) * 32768;                               \
    const char* Bs = lds + 65536 + ((TILE) & 1) * 32768;                       \
    if ((Q) == 0) {                                                            \
      _Pragma("unroll") for (int fj = 0; fj < 4; ++fj) {                       \
        const int r = wn * 64 + fj * 16 + lr;                                  \
        _Pragma("unroll") for (int kk = 0; kk < 2; ++kk)                       \
          bfr[fj][kk] = *(const short8*)(Bs + r * 128 +                        \
                                         (((kk * 4 + lk) ^ (r & 7)) << 4));    \
      }                                                                        \
    }                                                                          \
    short8 af[2][2];                                                           \
    _Pragma("unroll") for (int fl = 0; fl < 2; ++fl) {                         \
      const int r = wm * 128 + (Q) * 32 + fl * 16 + lr;                        \
      _Pragma("unroll") for (int kk = 0; kk < 2; ++kk)                         \
        af[fl][kk] = *(const short8*)(As + r * 128 +                           \
                                      (((kk * 4 + lk) ^ (r & 7)) << 4));       \
    }                                                                          \
    STG;                                                                       \
    if ((Q) == 0) asm volatile("s_waitcnt lgkmcnt(8)" ::: "memory");           \
    __builtin_amdgcn_s_barrier();                                              \
    __builtin_amdgcn_s_setprio(1);                                             \
    _Pragma("unroll") for (int kk = 0; kk < 2; ++kk)                           \
      _Pragma("unroll") for (int fl = 0; fl < 2; ++fl)                         \
        _Pragma("unroll") for (int fj = 0; fj < 4; ++fj)                       \
          acc[(Q) * 2 + fl][fj] = __builtin_amdgcn_mfma_f32_16x16x32_bf16(     \
              af[fl][kk], bfr[fj][kk], acc[(Q) * 2 + fl][fj], 0, 0, 0);        \
    __builtin_amdgcn_s_setprio(0);                                             \
    VMST;                                                                      \
    __builtin_amdgcn_s_barrier();                                              \
  } while (0)

__global__ __launch_bounds__(512, 2) void gemm_out(
    const unsigned short* __restrict__ G,    // [16384][256] bf16
    unsigned short* __restrict__ stb,        // [16384][256] bf16 (scratch)
    const unsigned short* __restrict__ xb,   // [16384][1024] bf16
    const unsigned short* __restrict__ wob,  // [1024][1280] bf16
    const float* __restrict__ Aarr,          // [256]
    const float* __restrict__ Cb,            // [1024]
    const float* __restrict__ Db,            // [1024]
    float* __restrict__ dout)                // [16384][1024] f32
{
  __shared__ char lds[131072];  // A: 2x32KB @0, B: 2x32KB @65536

  const int tid = threadIdx.x;
  const int wave = tid >> 6;
  const int lane = tid & 63;
  const int lr = lane & 15;
  const int lk = lane >> 4;
  const int wm = wave >> 2;  // 0..1
  const int wn = wave & 3;   // 0..3

  const int bs = ((blockIdx.x & 7) << 5) | (blockIdx.x >> 3);  // XCD swizzle
  const int m0 = (bs >> 2) * 256;
  const int n0 = (bs & 3) * 256;

  const char* stbB = (const char*)stb;
  const char* xbB  = (const char*)xb;
  const char* wobB = (const char*)wob;

  // staging with t_ord -> kt mapping: t<16 -> kt=t+4 (xb), t>=16 -> kt=t-16 (stb)
  auto stageA = [&](int t, int h) {
    if (t >= 20) return;
    const char* base;
    size_t str;
    size_t colb;
    if (t < 16) { base = xbB;  str = 2048; colb = (size_t)t * 128; }
    else        { base = stbB; str = 512;  colb = (size_t)(t - 16) * 128; }
    base += (size_t)m0 * str;
#pragma unroll
    for (int i2 = 0; i2 < 2; ++i2) {
      const int s = i2 * 512 + tid;
      const int r = s >> 3;
      const int cl = (s & 7) ^ (r & 7);
      gl_lds16(base + (size_t)(h * 128 + r) * str + colb + cl * 16,
               lds + ((t & 1) * 32768) + h * 16384 + i2 * 8192 + wave * 1024);
    }
  };
  auto stageB = [&](int t, int h) {
    if (t >= 20) return;
    const int kt = (t < 16) ? t + 4 : t - 16;
#pragma unroll
    for (int i2 = 0; i2 < 2; ++i2) {
      const int s = i2 * 512 + tid;
      const int r = s >> 3;
      const int cl = (s & 7) ^ (r & 7);
      gl_lds16(wobB + (size_t)(n0 + h * 128 + r) * 2560 + (size_t)kt * 128 + cl * 16,
               lds + 65536 + ((t & 1) * 32768) + h * 16384 + i2 * 8192 + wave * 1024);
    }
  };

  // ---- prologue staging FIRST (t_ord 0,1 = kt 4,5: xb/wob only) ----
  stageA(0, 0); stageA(0, 1);
  stageB(0, 0); stageB(0, 1);
  stageB(1, 0); stageB(1, 1);

  // ---- Phase 1: scan, two interleaved chains per thread ----
  {
    const int s  = tid >> 8;        // slot 0/1 (wave-uniform)
    const int n  = tid & 255;       // channel
    const int T0 = m0 & 4095;       // step offset within batch
    const int nw0 = (T0 == 0 && s == 0) ? 0 : 64;  // chain0 warmup (uniform)
    const int start0 = m0 + 64 * s - nw0;          // chain0: chunk s
    const int start1 = m0 + 64 * s + 64;           // chain1: chunk s+2 (nw=64)
    const unsigned short* g0 = G + (size_t)start0 * STATE + n;
    const unsigned short* g1 = G + (size_t)start1 * STATE + n;
    unsigned short* q0 = stb + (size_t)start0 * STATE + n;
    unsigned short* q1 = stb + (size_t)start1 * STATE + n;
    const float P = C2F * __builtin_amdgcn_exp2f(Aarr[n] * LOG2EF);
    const float mP2 = -2.0f * P;

    float r0 = 0.5f, r1 = 0.5f;
    constexpr int CH = 16;
    const int NC0 = (nw0 + 64) / CH;  // 4 or 8
    float cur0[CH], nxt0[CH], cur1[CH], nxt1[CH];
#pragma unroll
    for (int j = 0; j < CH; ++j) {
      cur0[j] = bf2f(g0[(size_t)j * STATE]);
      cur1[j] = bf2f(g1[(size_t)j * STATE]);
    }

    for (int c = 0; c < 8; ++c) {
      const bool a0 = (c < NC0);
      if (c + 1 < NC0) {
        const unsigned short* p = g0 + (size_t)(c + 1) * CH * STATE;
#pragma unroll
        for (int j = 0; j < CH; ++j) nxt0[j] = bf2f(p[(size_t)j * STATE]);
      }
      if (c + 1 < 8) {
        const unsigned short* p = g1 + (size_t)(c + 1) * CH * STATE;
#pragma unroll
        for (int j = 0; j < CH; ++j) nxt1[j] = bf2f(p[(size_t)j * STATE]);
      }
      const bool e0 = a0 && (c * CH >= nw0);
      const bool e1 = (c >= 4);
      unsigned short* qc0 = q0 + (size_t)c * CH * STATE;
      unsigned short* qc1 = q1 + (size_t)c * CH * STATE;
#pragma unroll
      for (int j = 0; j < CH; ++j) {
        if (a0) {  // chain 0 step (independent of chain 1 -> pipelined)
          const float t0 = fmaf(mP2, r0, cur0[j]);
          const float x0 = __builtin_amdgcn_exp2f(t0);
          r0 = __builtin_amdgcn_rcpf(1.0f + x0);
          if (e0) qc0[(size_t)j * STATE] = f2bf(fmaf(-2.0f, r0, 1.0f));
        }
        {          // chain 1 step
          const float t1 = fmaf(mP2, r1, cur1[j]);
          const float x1 = __builtin_amdgcn_exp2f(t1);
          r1 = __builtin_amdgcn_rcpf(1.0f + x1);
          if (e1) qc1[(size_t)j * STATE] = f2bf(fmaf(-2.0f, r1, 1.0f));
        }
      }
      if (c + 1 < NC0) {
#pragma unroll
        for (int j = 0; j < CH; ++j) cur0[j] = nxt0[j];
      }
      if (c + 1 < 8) {
#pragma unroll
        for (int j = 0; j < CH; ++j) cur1[j] = nxt1[j];
      }
    }
  }
  VMC(0);                           // stb stores + prologue staging complete
  __builtin_amdgcn_s_barrier();     // whole block's stb slice visible

  // ---- Phase 2: frozen r6 K-loop over t_ord 0..19 ----
  f32x4 acc[8][4];
#pragma unroll
  for (int i = 0; i < 8; ++i)
#pragma unroll
    for (int j = 0; j < 4; ++j) acc[i][j] = (f32x4){0.f, 0.f, 0.f, 0.f};

  short8 bfr[4][2];
  for (int i = 0; i < 10; ++i) {
    const int e = 2 * i, o = e + 1;
    PH(e, 0, stageA(o, 0), );
    PH(e, 1, stageA(o, 1), );
    PH(e, 2, stageB(e + 2, 0), );
    PH(e, 3, stageB(e + 2, 1), if (i == 9) { VMC(0); } else { VMC(4); });
    PH(o, 0, stageA(e + 2, 0), );
    PH(o, 1, stageA(e + 2, 1), );
    PH(o, 2, stageB(o + 2, 0), );
    PH(o, 3, stageB(o + 2, 1), VMC(4));
  }

  // ---- epilogue: dout = acc + Cb + Db ----
#pragma unroll
  for (int fj = 0; fj < 4; ++fj) {
    const int col = n0 + wn * 64 + fj * 16 + lr;
    const float cb = Cb[col] + Db[col];
#pragma unroll
    for (int m = 0; m < 8; ++m) {
      const int rowb = m0 + wm * 128 + m * 16 + lk * 4;
#pragma unroll
      for (int j = 0; j < 4; ++j)
        dout[(size_t)(rowb + j) * DIM + col] = acc[m][fj][j] + cb;
    }
  }
}

extern "C" void kernel_launch(void* const* d_in, const int* in_sizes, int n_in,
                              void* d_out, int out_size, void* d_ws, size_t ws_size,
                              hipStream_t stream) {
  const float* x  = (const float*)d_in[0];
  const float* A  = (const float*)d_in[1];
  const float* Bw = (const float*)d_in[2];
  const float* Bb = (const float*)d_in[3];
  const float* Cw = (const float*)d_in[4];
  const float* Cb = (const float*)d_in[5];
  const float* Dw = (const float*)d_in[6];
  const float* Db = (const float*)d_in[7];
  float* dout = (float*)d_out;

  char* ws = (char*)d_ws;
  unsigned short* xb   = (unsigned short*)(ws);              // 33,554,432 B
  unsigned short* bwb  = (unsigned short*)(ws + 33554432);   //    524,288 B
  unsigned short* wob  = (unsigned short*)(ws + 34078720);   //  2,621,440 B
  unsigned short* G    = (unsigned short*)(ws + 36700160);   //  8,388,608 B
  unsigned short* stb  = (unsigned short*)(ws + 53477376);   //  8,388,608 B -> 61,865,984

  // 1) weight conversion: bwb + wob
  convert_w<<<512, 256, 0, stream>>>(Bw, Cw, Dw, bwb, wob);
  // 2) fused: G(bf16) = (x @ Bw^T)*C2 + bias ; xb = bf16(x)
  gemm_GX<<<512, 256, 0, stream>>>(x, bwb, Bb, A, G, xb);
  // 3) fused: ILP scan (G -> stb slice) + dout = [states|x]@[Cw|Dw]^T + bias
  gemm_out<<<256, 512, 0, stream>>>(G, stb, xb, wob, A, Cb, Db, dout);
}

// Round 18
// 89.198 us; speedup vs baseline: 1.0615x; 1.0615x over previous
//
#include <hip/hip_runtime.h>
#include <hip/hip_bf16.h>

#define DIM 1024
#define STATE 256
#define BATCH 4
#define SEQ 4096
#define M_TOT (BATCH * SEQ)  // 16384

typedef short short8 __attribute__((ext_vector_type(8)));
typedef float f32x4 __attribute__((ext_vector_type(4)));

__device__ __forceinline__ unsigned short f2bf(float f) {
  unsigned int u = __float_as_uint(f);
  u += 0x7fff + ((u >> 16) & 1);  // RNE
  return (unsigned short)(u >> 16);
}

__device__ __forceinline__ float bf2f(unsigned short u) {
  return __uint_as_float((unsigned int)u << 16);
}

__device__ __forceinline__ void gl_lds16(const void* g, void* l) {
  __builtin_amdgcn_global_load_lds(
      (const __attribute__((address_space(1))) void*)g,
      (__attribute__((address_space(3))) void*)l, 16, 0, 0);
}

#define C2F 2.8853900817779268f   // 2*log2(e)
#define LOG2EF 1.4426950408889634f
#define VMC(N) asm volatile("s_waitcnt vmcnt(" #N ")" ::: "memory")

// ---------------- convert_w: Bw -> bwb ; [Cw|Dw] -> wob (r16, unchanged) -----
__global__ __launch_bounds__(256) void convert_w(
    const float* __restrict__ Bw, const float* __restrict__ Cw,
    const float* __restrict__ Dw, unsigned short* __restrict__ bwb,
    unsigned short* __restrict__ wob) {
  const int bx = blockIdx.x;
  const int t = threadIdx.x;
  if (bx < 256) {
    const int c = t * 4;
    const float4 v = *(const float4*)(Bw + (size_t)bx * DIM + c);
    *(ushort4*)(bwb + (size_t)bx * DIM + c) =
        make_ushort4(f2bf(v.x), f2bf(v.y), f2bf(v.z), f2bf(v.w));
  } else {
    const int e0 = (bx - 256) * 4;
#pragma unroll
    for (int rr = 0; rr < 4; ++rr) {
      const int e = e0 + rr;
      if (t < 64) {
        const float4 v = *(const float4*)(Cw + (size_t)e * STATE + t * 4);
        *(ushort4*)(wob + (size_t)e * 1280 + t * 4) =
            make_ushort4(f2bf(v.x), f2bf(v.y), f2bf(v.z), f2bf(v.w));
      }
      const float4 v = *(const float4*)(Dw + (size_t)e * DIM + t * 4);
      *(ushort4*)(wob + (size_t)e * 1280 + 256 + t * 4) =
          make_ushort4(f2bf(v.x), f2bf(v.y), f2bf(v.z), f2bf(v.w));
    }
  }
}

// ---------------- gemm_GX v4.1 (r15/r16, unchanged): G + xb ------------------
__global__ __launch_bounds__(256, 2) void gemm_GX(
    const float* __restrict__ x,             // [16384][1024] f32
    const unsigned short* __restrict__ bwb,  // [256][1024] bf16
    const float* __restrict__ Bb,            // [256]
    const float* __restrict__ A,             // [256]
    unsigned short* __restrict__ G,          // [16384][256] bf16 (out)
    unsigned short* __restrict__ xb)         // [16384][1024] bf16 (out)
{
  __shared__ char lds[81920];  // 2 slots x 40960 (A 8KB @0, B 32KB @8192)

  const int tid = threadIdx.x;
  const int wave = tid >> 6;
  const int lane = tid & 63;
  const int lr = lane & 15;
  const int lk = lane >> 4;
  const int m0 = blockIdx.x * 32;

  f32x4 acc[2][4];
#pragma unroll
  for (int i = 0; i < 2; ++i)
#pragma unroll
    for (int j = 0; j < 4; ++j) acc[i][j] = (f32x4){0.f, 0.f, 0.f, 0.f};

  const char* xB  = (const char*)x;
  const char* bwB = (const char*)bwb;
  char* xbB = (char*)xb;

  auto stage = [&](int kt) {
    if (kt >= 16) return;
    char* slot = lds + (kt & 1) * 40960;
#pragma unroll
    for (int i = 0; i < 2; ++i) {   // A: [32 rows][256B f32], XOR(r&7)
      const int s = i * 256 + tid;
      const int r = s >> 4;
      const int c = (s & 15) ^ (r & 7);
      gl_lds16(xB + (size_t)(m0 + r) * 4096 + (size_t)kt * 256 + c * 16,
               slot + i * 4096 + wave * 1024);
    }
#pragma unroll
    for (int i = 0; i < 8; ++i) {   // B: [256 rows][128B bf16], XOR(r&7)
      const int s = i * 256 + tid;
      const int r = s >> 3;
      const int c = (s & 7) ^ (r & 7);
      gl_lds16(bwB + (size_t)r * 2048 + (size_t)kt * 128 + c * 16,
               slot + 8192 + i * 4096 + wave * 1024);
    }
  };

  stage(0);
  VMC(0);
  __builtin_amdgcn_s_barrier();
  stage(1);

  for (int t = 0; t < 16; ++t) {
    const char* As = lds + (t & 1) * 40960;
    const char* Bs = As + 8192;

    short8 af[2][2];  // [kk][f]
#pragma unroll
    for (int kk = 0; kk < 2; ++kk)
#pragma unroll
      for (int f = 0; f < 2; ++f) {
        const int row = f * 16 + lr;
        const int sw = row & 7;
        const f32x4 a0 = *(const f32x4*)(As + row * 256 + (((kk * 8 + 2 * lk)     ^ sw) << 4));
        const f32x4 a1 = *(const f32x4*)(As + row * 256 + (((kk * 8 + 2 * lk + 1) ^ sw) << 4));
        short8 v;
#pragma unroll
        for (int j = 0; j < 4; ++j) {
          v[j]     = (short)f2bf(a0[j]);
          v[4 + j] = (short)f2bf(a1[j]);
        }
        af[kk][f] = v;
      }

    if ((t & 3) == wave) {  // early xb store
#pragma unroll
      for (int kk = 0; kk < 2; ++kk)
#pragma unroll
        for (int f = 0; f < 2; ++f) {
          const int row = f * 16 + lr;
          *(short8*)(xbB + (size_t)(m0 + row) * 2048 +
                     (size_t)t * 128 + kk * 64 + lk * 16) = af[kk][f];
        }
    }

    short8 bfr[2][4];
#pragma unroll
    for (int kk = 0; kk < 2; ++kk)
#pragma unroll
      for (int fj = 0; fj < 4; ++fj) {
        const int n = wave * 64 + fj * 16 + lr;
        bfr[kk][fj] = *(const short8*)(Bs + n * 128 + (((kk * 4 + lk) ^ (n & 7)) << 4));
      }
#pragma unroll
    for (int kk = 0; kk < 2; ++kk)
#pragma unroll
      for (int f = 0; f < 2; ++f)
#pragma unroll
        for (int fj = 0; fj < 4; ++fj)
          acc[f][fj] = __builtin_amdgcn_mfma_f32_16x16x32_bf16(
              af[kk][f], bfr[kk][fj], acc[f][fj], 0, 0, 0);

    if (t < 15) {
      VMC(0);
      __builtin_amdgcn_s_barrier();
      stage(t + 2);
    }
  }

#pragma unroll
  for (int fj = 0; fj < 4; ++fj) {
    const int cg = wave * 64 + fj * 16 + lr;
    const float bbv = fmaf(Bb[cg], C2F,
                           C2F * __builtin_amdgcn_exp2f(A[cg] * LOG2EF));
#pragma unroll
    for (int f = 0; f < 2; ++f)
#pragma unroll
      for (int j = 0; j < 4; ++j) {
        const int rg = m0 + f * 16 + lk * 4 + j;
        G[(size_t)rg * STATE + cg] = f2bf(fmaf(acc[f][fj][j], C2F, bbv));
      }
  }
}

// ---------------- gemm_out v6: r16 scan head + wob-prologue hoist ------------
// = r16 v4 (best measured, 89.46 total) with ONE change: the wob-only
// prologue stages B(0),B(1) (no stb dependency) issue BEFORE the scan head so
// their fill hides under the ~10us scan; the stb-dependent stageA(0) issues
// after the scan's VMC(0)+barrier with its own drain. K-loop byte-identical
// r6 (loop entry now has outstanding=0, strictly earlier-drained than r6's
// proven state; every PH VMC(4) forcing set unchanged or superset).
#define PH(TILE, Q, STG, VMST)                                                 \
  do {                                                                         \
    const char* As = lds + ((TILE) & 1) * 32768;                               \
    const char* Bs = lds + 65536 + ((TILE) & 1) * 32768;                       \
    if ((Q) == 0) {                                                            \
      _Pragma("unroll") for (int fj = 0; fj < 4; ++fj) {                       \
        const int r = wn * 64 + fj * 16 + lr;                                  \
        _Pragma("unroll") for (int kk = 0; kk < 2; ++kk)                       \
          bfr[fj][kk] = *(const short8*)(Bs + r * 128 +                        \
                                         (((kk * 4 + lk) ^ (r & 7)) << 4));    \
      }                                                                        \
    }                                                                          \
    short8 af[2][2];                                                           \
    _Pragma("unroll") for (int fl = 0; fl < 2; ++fl) {                         \
      const int r = wm * 128 + (Q) * 32 + fl * 16 + lr;                        \
      _Pragma("unroll") for (int kk = 0; kk < 2; ++kk)                         \
        af[fl][kk] = *(const short8*)(As + r * 128 +                           \
                                      (((kk * 4 + lk) ^ (r & 7)) << 4));       \
    }                                                                          \
    STG;                                                                       \
    if ((Q) == 0) asm volatile("s_waitcnt lgkmcnt(8)" ::: "memory");           \
    __builtin_amdgcn_s_barrier();                                              \
    __builtin_amdgcn_s_setprio(1);                                             \
    _Pragma("unroll") for (int kk = 0; kk < 2; ++kk)                           \
      _Pragma("unroll") for (int fl = 0; fl < 2; ++fl)                         \
        _Pragma("unroll") for (int fj = 0; fj < 4; ++fj)                       \
          acc[(Q) * 2 + fl][fj] = __builtin_amdgcn_mfma_f32_16x16x32_bf16(     \
              af[fl][kk], bfr[fj][kk], acc[(Q) * 2 + fl][fj], 0, 0, 0);        \
    __builtin_amdgcn_s_setprio(0);                                             \
    VMST;                                                                      \
    __builtin_amdgcn_s_barrier();                                              \
  } while (0)

__global__ __launch_bounds__(512, 2) void gemm_out(
    const unsigned short* __restrict__ G,    // [16384][256] bf16
    unsigned short* __restrict__ stb,        // [16384][256] bf16 (scratch)
    const unsigned short* __restrict__ xb,   // [16384][1024] bf16
    const unsigned short* __restrict__ wob,  // [1024][1280] bf16
    const float* __restrict__ Aarr,          // [256]
    const float* __restrict__ Cb,            // [1024]
    const float* __restrict__ Db,            // [1024]
    float* __restrict__ dout)                // [16384][1024] f32
{
  __shared__ char lds[131072];  // A: 2x32KB @0, B: 2x32KB @65536

  const int tid = threadIdx.x;
  const int wave = tid >> 6;
  const int lane = tid & 63;
  const int lr = lane & 15;
  const int lk = lane >> 4;
  const int wm = wave >> 2;  // 0..1
  const int wn = wave & 3;   // 0..3

  const int bs = ((blockIdx.x & 7) << 5) | (blockIdx.x >> 3);  // XCD swizzle
  const int m0 = (bs >> 2) * 256;
  const int n0 = (bs & 3) * 256;

  const char* stbB = (const char*)stb;
  const char* xbB  = (const char*)xb;
  const char* wobB = (const char*)wob;

  auto stageA = [&](int kt, int h) {
    if (kt >= 20) return;
    const char* base;
    size_t str;
    size_t colb;
    if (kt < 4) { base = stbB; str = 512;  colb = (size_t)kt * 128; }
    else        { base = xbB;  str = 2048; colb = (size_t)(kt - 4) * 128; }
    base += (size_t)m0 * str;
#pragma unroll
    for (int i2 = 0; i2 < 2; ++i2) {
      const int s = i2 * 512 + tid;
      const int r = s >> 3;
      const int cl = (s & 7) ^ (r & 7);
      gl_lds16(base + (size_t)(h * 128 + r) * str + colb + cl * 16,
               lds + ((kt & 1) * 32768) + h * 16384 + i2 * 8192 + wave * 1024);
    }
  };
  auto stageB = [&](int kt, int h) {
    if (kt >= 20) return;
#pragma unroll
    for (int i2 = 0; i2 < 2; ++i2) {
      const int s = i2 * 512 + tid;
      const int r = s >> 3;
      const int cl = (s & 7) ^ (r & 7);
      gl_lds16(wobB + (size_t)(n0 + h * 128 + r) * 2560 + (size_t)kt * 128 + cl * 16,
               lds + 65536 + ((kt & 1) * 32768) + h * 16384 + i2 * 8192 + wave * 1024);
    }
  };

  // ---- wob-only prologue staging BEFORE scan (fills under it) ----
  stageB(0, 0); stageB(0, 1);
  stageB(1, 0); stageB(1, 1);

  // ---- Phase 1: in-block scan -> stb rows [m0, m0+256) (r16, unchanged) ----
  {
    const int c2 = tid >> 8;        // chunk 0 or 1 (wave-uniform)
    const int n  = tid & 255;       // channel
    const int T0 = m0 & 4095;       // step offset within batch
    const int startT = (c2 == 0) ? ((T0 == 0) ? 0 : T0 - 64) : T0 + 64;
    const int nw = (c2 == 0 && T0 == 0) ? 0 : 64;   // warmup steps
    const int total = nw + 128;
    const int mstart = (m0 - T0) + startT;          // absolute row
    const unsigned short* g = G + (size_t)mstart * STATE + n;
    unsigned short* q = stb + (size_t)mstart * STATE + n;
    const float P = C2F * __builtin_amdgcn_exp2f(Aarr[n] * LOG2EF);
    const float mP2 = -2.0f * P;

    float r = 0.5f;
    constexpr int CH = 16;
    float cur[CH], nxt[CH];
#pragma unroll
    for (int j = 0; j < CH; ++j) cur[j] = bf2f(g[(size_t)j * STATE]);

    const int NC = total / CH;      // 8 or 12 (wave-uniform)
    for (int c = 0; c < NC; ++c) {
      if (c + 1 < NC) {
        const unsigned short* pn = g + (size_t)(c + 1) * CH * STATE;
#pragma unroll
        for (int j = 0; j < CH; ++j) nxt[j] = bf2f(pn[(size_t)j * STATE]);
      }
      if (c * CH >= nw) {           // emit
        unsigned short* qc = q + (size_t)c * CH * STATE;
#pragma unroll
        for (int j = 0; j < CH; ++j) {
          const float t = fmaf(mP2, r, cur[j]);
          const float e = __builtin_amdgcn_exp2f(t);
          r = __builtin_amdgcn_rcpf(1.0f + e);
          const float s = fmaf(-2.0f, r, 1.0f);
          qc[(size_t)j * STATE] = f2bf(s);
        }
      } else {                      // warmup
#pragma unroll
        for (int j = 0; j < CH; ++j) {
          const float t = fmaf(mP2, r, cur[j]);
          const float e = __builtin_amdgcn_exp2f(t);
          r = __builtin_amdgcn_rcpf(1.0f + e);
        }
      }
      if (c + 1 < NC) {
#pragma unroll
        for (int j = 0; j < CH; ++j) cur[j] = nxt[j];
      }
    }
  }
  VMC(0);                           // stb stores (+ B stages) complete
  __builtin_amdgcn_s_barrier();     // whole block's stb slice visible

  // ---- stb-dependent prologue stage + drain ----
  stageA(0, 0); stageA(0, 1);
  VMC(0);
  __builtin_amdgcn_s_barrier();

  // ---- Phase 2: frozen r6 K-loop ----
  f32x4 acc[8][4];
#pragma unroll
  for (int i = 0; i < 8; ++i)
#pragma unroll
    for (int j = 0; j < 4; ++j) acc[i][j] = (f32x4){0.f, 0.f, 0.f, 0.f};

  short8 bfr[4][2];
  for (int i = 0; i < 10; ++i) {
    const int e = 2 * i, o = e + 1;
    PH(e, 0, stageA(o, 0), );
    PH(e, 1, stageA(o, 1), );
    PH(e, 2, stageB(e + 2, 0), );
    PH(e, 3, stageB(e + 2, 1), if (i == 9) { VMC(0); } else { VMC(4); });
    PH(o, 0, stageA(e + 2, 0), );
    PH(o, 1, stageA(e + 2, 1), );
    PH(o, 2, stageB(o + 2, 0), );
    PH(o, 3, stageB(o + 2, 1), VMC(4));
  }

  // ---- epilogue: dout = acc + Cb + Db ----
#pragma unroll
  for (int fj = 0; fj < 4; ++fj) {
    const int col = n0 + wn * 64 + fj * 16 + lr;
    const float cb = Cb[col] + Db[col];
#pragma unroll
    for (int m = 0; m < 8; ++m) {
      const int rowb = m0 + wm * 128 + m * 16 + lk * 4;
#pragma unroll
      for (int j = 0; j < 4; ++j)
        dout[(size_t)(rowb + j) * DIM + col] = acc[m][fj][j] + cb;
    }
  }
}

extern "C" void kernel_launch(void* const* d_in, const int* in_sizes, int n_in,
                              void* d_out, int out_size, void* d_ws, size_t ws_size,
                              hipStream_t stream) {
  const float* x  = (const float*)d_in[0];
  const float* A  = (const float*)d_in[1];
  const float* Bw = (const float*)d_in[2];
  const float* Bb = (const float*)d_in[3];
  const float* Cw = (const float*)d_in[4];
  const float* Cb = (const float*)d_in[5];
  const float* Dw = (const float*)d_in[6];
  const float* Db = (const float*)d_in[7];
  float* dout = (float*)d_out;

  char* ws = (char*)d_ws;
  unsigned short* xb   = (unsigned short*)(ws);              // 33,554,432 B
  unsigned short* bwb  = (unsigned short*)(ws + 33554432);   //    524,288 B
  unsigned short* wob  = (unsigned short*)(ws + 34078720);   //  2,621,440 B
  unsigned short* G    = (unsigned short*)(ws + 36700160);   //  8,388,608 B
  unsigned short* stb  = (unsigned short*)(ws + 53477376);   //  8,388,608 B -> 61,865,984

  // 1) weight conversion: bwb + wob
  convert_w<<<512, 256, 0, stream>>>(Bw, Cw, Dw, bwb, wob);
  // 2) fused: G(bf16) = (x @ Bw^T)*C2 + bias ; xb = bf16(x)
  gemm_GX<<<512, 256, 0, stream>>>(x, bwb, Bb, A, G, xb);
  // 3) fused: scan (G -> stb slice) + dout = [states|x]@[Cw|Dw]^T + bias
  gemm_out<<<256, 512, 0, stream>>>(G, stb, xb, wob, A, Cb, Db, dout);
}